// Round 6
// baseline (84.269 us; speedup 1.0000x reference)
//
#include <hip/hip_runtime.h>
#include <math.h>

#define NTHREADS 256

// Geometry (fixed by the problem): B=8, C=32, H=W=64, P=4, N=8. All f32.
// Grid: B*C*SPLIT blocks; each block owns 16 rows of one (b,c) plane.
// LDS pair tile: pair[y][x] = (v[y][x], v[y][min(x+1,63)]) so one bilinear
// sample = 2x ds_read_b64 (rows y0,y1) instead of 4x b32.
__global__ __launch_bounds__(NTHREADS) void lbp_fwd(
    const float* __restrict__ xg,     // (8,32,64,64) f32
    const float* __restrict__ rawg,   // (4,8,2) f32
    const float* __restrict__ pwg,    // (4,8) f32
    float* __restrict__ outg)         // (8,128,64,64) f32
{
    const int C = 32, H = 64, P = 4, N = 8;
    const int RO = 16;                 // rows owned per block

    __shared__ float2 pair[21][64];    // 16 owned rows + up to 5 halo rows
    __shared__ float2 offs[32];
    __shared__ float  wgt[32];

    int bid = blockIdx.x;
    int s = bid & 3;                   // row-band
    int c = (bid >> 2) & (C - 1);
    int b = bid >> 7;
    int r0 = s * RO;
    int lo = max(0, r0 - 2);
    int hi = min(H, r0 + RO + 3);
    int rows = hi - lo;

    int tid = threadIdx.x;

    // offsets = clip(2*tanh(raw/2), -2, 2). /2 and *2 exact; tanh in double
    // then round to f32 ~= correctly-rounded f32 tanh (closest proxy for np).
    if (tid < P * N) {
        float rx = rawg[2 * tid];
        float ry = rawg[2 * tid + 1];
        float ox = 2.0f * (float)tanh((double)(rx * 0.5f));
        float oy = 2.0f * (float)tanh((double)(ry * 0.5f));
        ox = fminf(fmaxf(ox, -2.0f), 2.0f);
        oy = fminf(fmaxf(oy, -2.0f), 2.0f);
        offs[tid] = make_float2(ox, oy);
        wgt[tid]  = pwg[tid];
    }

    // Stage pair tile.
    const float* xp = xg + (((b * C) + c) << 12);
    for (int idx = tid; idx < rows * 64; idx += NTHREADS) {
        int y = idx >> 6, xx = idx & 63;
        const float* rowp = xp + ((lo + y) << 6);
        float a  = rowp[xx];
        float bb = rowp[min(xx + 1, 63)];
        pair[y][xx] = make_float2(a, bb);
    }
    __syncthreads();

    int w  = tid & 63;
    int hb = tid >> 6;                 // 0..3; uniform within a wave
    float wf = (float)w;

    float xc[4], hf[4];
    int   hrow[4];
    #pragma unroll
    for (int k = 0; k < 4; ++k) {
        int h = r0 + (hb << 2) + k;
        hrow[k] = h;
        hf[k]   = (float)h;
        xc[k]   = pair[h - lo][w].x;
    }

    for (int p = 0; p < P; ++p) {
        float acc[4] = {0.f, 0.f, 0.f, 0.f};
        for (int j = 0; j < N; ++j) {
            int pn = p * N + j;
            float2 o = offs[pn];
            float wg = wgt[pn];
            // x-side hoisted per pn (w fixed per thread). Replicates
            // clip(arange+off,0,63), floor, frac — all rounding-exact ops.
            float px   = fminf(fmaxf(__fadd_rn(wf, o.x), 0.0f), 63.0f);
            float x0f  = floorf(px);
            float wx   = __fsub_rn(px, x0f);   // exact
            float omwx = __fsub_rn(1.0f, wx);  // matches reference op
            int   x0i  = (int)x0f;
            #pragma unroll
            for (int k = 0; k < 4; ++k) {
                float py   = fminf(fmaxf(__fadd_rn(hf[k], o.y), 0.0f), 63.0f);
                float y0f  = floorf(py);
                float wy   = __fsub_rn(py, y0f);   // exact
                float omwy = __fsub_rn(1.0f, wy);
                int   y0i  = (int)y0f;
                int   y1i  = min(y0i + 1, 63);
                float2 rv0 = pair[y0i - lo][x0i];
                float2 rv1 = pair[y1i - lo][x0i];
                // Exact reference op order, no FMA contraction:
                float gx0 = __fadd_rn(__fmul_rn(rv0.x, omwx), __fmul_rn(rv0.y, wx));
                float gx1 = __fadd_rn(__fmul_rn(rv1.x, omwx), __fmul_rn(rv1.y, wx));
                float sam = __fadd_rn(__fmul_rn(gx0, omwy), __fmul_rn(gx1, wy));
                float diff = __fsub_rn(sam, xc[k]);
                acc[k] += (diff > 0.0f) ? wg : 0.0f;   // forward == b_hard exactly
            }
        }
        unsigned int obase = (((unsigned)(b * P + p) * C + c) << 12);
        #pragma unroll
        for (int k = 0; k < 4; ++k) {
            outg[obase + (hrow[k] << 6) + w] = acc[k];
        }
    }
}

extern "C" void kernel_launch(void* const* d_in, const int* in_sizes, int n_in,
                              void* d_out, int out_size, void* d_ws, size_t ws_size,
                              hipStream_t stream) {
    const float* x   = (const float*)d_in[0];
    const float* raw = (const float*)d_in[1];
    const float* pw  = (const float*)d_in[2];
    float* out = (float*)d_out;
    (void)in_sizes; (void)n_in; (void)out_size; (void)d_ws; (void)ws_size;

    dim3 grid(8 * 32 * 4);   // B * C * SPLIT
    dim3 block(NTHREADS);
    hipLaunchKernelGGL(lbp_fwd, grid, block, 0, stream, x, raw, pw, out);
}

// Round 8
// 82.623 us; speedup vs baseline: 1.0199x; 1.0199x over previous
//
#include <hip/hip_runtime.h>
#include <math.h>

#define NTHREADS 256

// Geometry: B=8, C=32, H=W=64, P=4, N=8. All f32.
// SPLIT=8: grid 2048 = B*C*8; each block owns 8 rows of one (b,c) plane.
// 2048 blocks / 256 CU = 8 blocks/CU = 32 waves/CU (max occupancy) for
// latency hiding. LDS pair tile: pair[y][x] = (v[x], v[min(x+1,63)]) so one
// bilinear sample = 2x ds_read_b64.
__global__ __launch_bounds__(NTHREADS) void lbp_fwd(
    const float* __restrict__ xg,     // (8,32,64,64) f32
    const float* __restrict__ rawg,   // (4,8,2) f32
    const float* __restrict__ pwg,    // (4,8) f32
    float* __restrict__ outg)         // (8,128,64,64) f32
{
    const int C = 32, H = 64, P = 4, N = 8;
    const int RO = 8;                  // rows owned per block

    __shared__ float2 pair[13][64];    // 8 owned rows + up to 5 halo rows
    __shared__ float2 offs[32];
    __shared__ float  wgt[32];

    int bid = blockIdx.x;
    int s = bid & 7;                   // row-band
    int c = (bid >> 3) & (C - 1);
    int b = bid >> 8;
    int r0 = s * RO;
    int lo = max(0, r0 - 2);
    int hi = min(H, r0 + RO + 3);
    int rows = hi - lo;

    int tid = threadIdx.x;

    // offsets = clip(2*tanh(raw/2), -2, 2). /2 and *2 exact; tanh in double
    // then round to f32 ~= correctly-rounded f32 tanh (proxy for np).
    // All 2048 blocks are co-resident, so this redundant compute costs one
    // concurrent ~0.3us, cheaper than a separate dispatch (~2us in-graph).
    if (tid < P * N) {
        float rx = rawg[2 * tid];
        float ry = rawg[2 * tid + 1];
        float ox = 2.0f * (float)tanh((double)(rx * 0.5f));
        float oy = 2.0f * (float)tanh((double)(ry * 0.5f));
        ox = fminf(fmaxf(ox, -2.0f), 2.0f);
        oy = fminf(fmaxf(oy, -2.0f), 2.0f);
        offs[tid] = make_float2(ox, oy);
        wgt[tid]  = pwg[tid];
    }

    // Stage pair tile (<= 13 rows x 64).
    const float* xp = xg + (((b * C) + c) << 12);
    for (int idx = tid; idx < rows * 64; idx += NTHREADS) {
        int y = idx >> 6, xx = idx & 63;
        const float* rowp = xp + ((lo + y) << 6);
        float a  = rowp[xx];
        float bb = rowp[min(xx + 1, 63)];
        pair[y][xx] = make_float2(a, bb);
    }
    __syncthreads();

    int w  = tid & 63;
    int hb = tid >> 6;                 // 0..3; uniform within a wave
    float wf = (float)w;

    float xc[2], hf[2];
    int   hrow[2];
    #pragma unroll
    for (int k = 0; k < 2; ++k) {
        int h = r0 + (hb << 1) + k;    // 4 waves x 2 rows = 8 owned rows
        hrow[k] = h;
        hf[k]   = (float)h;
        xc[k]   = pair[h - lo][w].x;
    }

    for (int p = 0; p < P; ++p) {
        float acc[2] = {0.f, 0.f};
        #pragma unroll 2
        for (int j = 0; j < N; ++j) {
            int pn = p * N + j;
            float2 o = offs[pn];
            float wg = wgt[pn];
            // x-side hoisted per pn (w fixed per thread). Replicates
            // clip(arange+off,0,63), floor, frac — rounding-exact ops.
            float px   = fminf(fmaxf(__fadd_rn(wf, o.x), 0.0f), 63.0f);
            float x0f  = floorf(px);
            float wx   = __fsub_rn(px, x0f);   // exact
            float omwx = __fsub_rn(1.0f, wx);  // matches reference op
            int   x0i  = (int)x0f;
            #pragma unroll
            for (int k = 0; k < 2; ++k) {
                float py   = fminf(fmaxf(__fadd_rn(hf[k], o.y), 0.0f), 63.0f);
                float y0f  = floorf(py);
                float wy   = __fsub_rn(py, y0f);   // exact
                float omwy = __fsub_rn(1.0f, wy);
                int   y0i  = (int)y0f;
                int   y1i  = min(y0i + 1, 63);
                float2 rv0 = pair[y0i - lo][x0i];
                float2 rv1 = pair[y1i - lo][x0i];
                // Exact reference op order, no FMA contraction:
                float gx0 = __fadd_rn(__fmul_rn(rv0.x, omwx), __fmul_rn(rv0.y, wx));
                float gx1 = __fadd_rn(__fmul_rn(rv1.x, omwx), __fmul_rn(rv1.y, wx));
                float sam = __fadd_rn(__fmul_rn(gx0, omwy), __fmul_rn(gx1, wy));
                float diff = __fsub_rn(sam, xc[k]);
                acc[k] += (diff > 0.0f) ? wg : 0.0f;   // forward == b_hard exactly
            }
        }
        unsigned int obase = (((unsigned)(b * P + p) * C + c) << 12);
        #pragma unroll
        for (int k = 0; k < 2; ++k) {
            outg[obase + (hrow[k] << 6) + w] = acc[k];
        }
    }
}

extern "C" void kernel_launch(void* const* d_in, const int* in_sizes, int n_in,
                              void* d_out, int out_size, void* d_ws, size_t ws_size,
                              hipStream_t stream) {
    const float* x   = (const float*)d_in[0];
    const float* raw = (const float*)d_in[1];
    const float* pw  = (const float*)d_in[2];
    float* out = (float*)d_out;
    (void)in_sizes; (void)n_in; (void)out_size; (void)d_ws; (void)ws_size;

    dim3 grid(8 * 32 * 8);   // B * C * SPLIT
    dim3 block(NTHREADS);
    hipLaunchKernelGGL(lbp_fwd, grid, block, 0, stream, x, raw, pw, out);
}